// Round 1
// baseline (1006.857 us; speedup 1.0000x reference)
//
#include <hip/hip_runtime.h>
#include <math.h>

#define NB   16
#define NPTS 2048
#define KNBR 20
#define NROWS (NB*NPTS)          // 32768
#define CONV_M ((double)(NB)*(double)(NPTS)*(double)(KNBR))
#define ROW_M  ((double)NROWS)
#define BN_EPS 1e-5
#define LSLOPE 0.2f

__device__ __forceinline__ float lrelu(float v) { return v >= 0.f ? v : LSLOPE * v; }

// ---------------------------------------------------------------------------
// KNN: per query, top-20 VALUES via branch-guarded min/max cascade (pass 1),
// then index recovery with d >= thresh in ascending-m order (pass 2).
// Matches jax.lax.top_k set semantics incl. lower-index tie-break at boundary.
// ---------------------------------------------------------------------------
__global__ __launch_bounds__(256) void knn_kernel(const float* __restrict__ x,
                                                  int* __restrict__ idxo)
{
    __shared__ float4 pts[NPTS];   // 32 KB: {x,y,z,xx}
    const int b = blockIdx.x >> 3;
    const int qbase = (blockIdx.x & 7) * 256;
    const float* xb = x + (size_t)b * NPTS * 3;
    for (int i = threadIdx.x; i < NPTS; i += 256) {
        float px = xb[i*3+0], py = xb[i*3+1], pz = xb[i*3+2];
        float xx = __fadd_rn(__fadd_rn(__fmul_rn(px,px), __fmul_rn(py,py)), __fmul_rn(pz,pz));
        pts[i] = make_float4(px, py, pz, xx);
    }
    __syncthreads();
    const int n = qbase + (int)threadIdx.x;
    const float4 q = pts[n];

    float bestv[KNBR];
#pragma unroll
    for (int j = 0; j < KNBR; ++j) bestv[j] = -__builtin_inff();

    for (int m = 0; m < NPTS; ++m) {
        float4 pm = pts[m];
        float inner = __fadd_rn(__fadd_rn(__fmul_rn(q.x,pm.x), __fmul_rn(q.y,pm.y)), __fmul_rn(q.z,pm.z));
        float d = __fsub_rn(__fsub_rn(__fmul_rn(2.0f, inner), q.w), pm.w);
        if (d > bestv[KNBR-1]) {
            float t = d;
#pragma unroll
            for (int j = 0; j < KNBR; ++j) {
                float bj = bestv[j];
                float hi = fmaxf(bj, t);
                t = fminf(bj, t);
                bestv[j] = hi;
            }
        }
    }
    const float thresh = bestv[KNBR-1];
    int* op = idxo + ((size_t)b * NPTS + n) * KNBR;
    int cnt = 0;
    for (int m = 0; m < NPTS; ++m) {
        float4 pm = pts[m];
        float inner = __fadd_rn(__fadd_rn(__fmul_rn(q.x,pm.x), __fmul_rn(q.y,pm.y)), __fmul_rn(q.z,pm.z));
        float d = __fsub_rn(__fsub_rn(__fmul_rn(2.0f, inner), q.w), pm.w);
        if (d >= thresh && cnt < KNBR) { op[cnt] = m; ++cnt; }
    }
}

// ---------------------------------------------------------------------------
// Edge-conv: per point, feat[k][6]; h[k][o] = feat.cw_o ; track max/min over k.
// Also accumulate feat moments S1[6], S2[21] (double) for factored BN stats.
// Block = 256 = 4 waves; each wave does 8 points; grid = 32768/32.
// ---------------------------------------------------------------------------
__global__ __launch_bounds__(256) void feat_kernel(const float* __restrict__ x,
        const int* __restrict__ idx, const float* __restrict__ conv_w,
        float* __restrict__ maxh, float* __restrict__ minh, double* __restrict__ S)
{
    __shared__ float  featw[4][KNBR][6];
    __shared__ double sred[4][27];
    const int wv = threadIdx.x >> 6, lane = threadIdx.x & 63;
    float cw[6];
#pragma unroll
    for (int c = 0; c < 6; ++c) cw[c] = conv_w[lane*6 + c];
    int pa_ = 0, pb_ = 0;
    if (lane >= 6 && lane < 27) {      // pair (a<=b) enumeration, t = lane-6
        int t = lane - 6, a = 0;
        while (t >= 6 - a) { t -= 6 - a; ++a; }
        pa_ = a; pb_ = a + t;
    }
    double acc = 0.0;
    for (int i = 0; i < 8; ++i) {
        const int bp = blockIdx.x * 32 + wv * 8 + i;
        const int b = bp >> 11, n = bp & (NPTS - 1);
        const float* xb = x + (size_t)b * NPTS * 3;
        const float xi0 = xb[n*3+0], xi1 = xb[n*3+1], xi2 = xb[n*3+2];
        float f0=0,f1=0,f2=0,f3=0,f4=0,f5=0;
        if (lane < KNBR) {
            const int nj = idx[(size_t)bp * KNBR + lane];
            f0 = xb[nj*3+0] - xi0; f1 = xb[nj*3+1] - xi1; f2 = xb[nj*3+2] - xi2;
            f3 = xi0; f4 = xi1; f5 = xi2;
        }
        __syncthreads();                       // protect previous iter's reads
        if (lane < KNBR) {
            featw[wv][lane][0]=f0; featw[wv][lane][1]=f1; featw[wv][lane][2]=f2;
            featw[wv][lane][3]=f3; featw[wv][lane][4]=f4; featw[wv][lane][5]=f5;
        }
        __syncthreads();
        float vmax = -__builtin_inff(), vmin = __builtin_inff();
#pragma unroll
        for (int k = 0; k < KNBR; ++k) {
            float h = featw[wv][k][0] * cw[0];
            h = fmaf(featw[wv][k][1], cw[1], h);
            h = fmaf(featw[wv][k][2], cw[2], h);
            h = fmaf(featw[wv][k][3], cw[3], h);
            h = fmaf(featw[wv][k][4], cw[4], h);
            h = fmaf(featw[wv][k][5], cw[5], h);
            vmax = fmaxf(vmax, h); vmin = fminf(vmin, h);
        }
        maxh[(size_t)bp*64 + lane] = vmax;
        minh[(size_t)bp*64 + lane] = vmin;
        if (lane < 6) {
            double s = 0;
#pragma unroll
            for (int k = 0; k < KNBR; ++k) s += (double)featw[wv][k][lane];
            acc += s;
        } else if (lane < 27) {
            double s = 0;
#pragma unroll
            for (int k = 0; k < KNBR; ++k)
                s += (double)featw[wv][k][pa_] * (double)featw[wv][k][pb_];
            acc += s;
        }
    }
    if (lane < 27) sred[wv][lane] = acc;
    __syncthreads();
    if (threadIdx.x < 27) {
        double tot = sred[0][threadIdx.x] + sred[1][threadIdx.x]
                   + sred[2][threadIdx.x] + sred[3][threadIdx.x];
        atomicAdd(&S[threadIdx.x], tot);
    }
}

// conv BN scale/shift from factored moments: mean_o = w_o.S1/M, E[h2]_o = w_o^T S2 w_o / M
__global__ void stats0_kernel(const double* __restrict__ S, const float* __restrict__ conv_w,
        const float* __restrict__ g, const float* __restrict__ bb,
        float* __restrict__ scale, float* __restrict__ shift)
{
    const int o = threadIdx.x;   // 64 threads
    double w[6];
#pragma unroll
    for (int c = 0; c < 6; ++c) w[c] = (double)conv_w[o*6 + c];
    double mean = 0.0;
#pragma unroll
    for (int c = 0; c < 6; ++c) mean += w[c] * S[c];
    mean /= CONV_M;
    double ey2 = 0.0;
    int t = 6;
#pragma unroll
    for (int a = 0; a < 6; ++a)
#pragma unroll
        for (int b2 = a; b2 < 6; ++b2) {
            double coef = (a == b2) ? 1.0 : 2.0;
            ey2 += coef * w[a] * w[b2] * S[t];
            ++t;
        }
    ey2 /= CONV_M;
    double var = ey2 - mean * mean;
    double sc = (double)g[o] / sqrt(var + BN_EPS);
    scale[o] = (float)sc;
    shift[o] = (float)((double)bb[o] - mean * sc);
}

__global__ void statsL_kernel(const double* __restrict__ sum, const double* __restrict__ sq,
        const float* __restrict__ g, const float* __restrict__ bt,
        float* __restrict__ scale, float* __restrict__ shift, int C)
{
    const int o = threadIdx.x;
    if (o >= C) return;
    double m = sum[o] / ROW_M;
    double v = sq[o] / ROW_M - m * m;
    double sc = (double)g[o] / sqrt(v + BN_EPS);
    scale[o] = (float)sc;
    shift[o] = (float)((double)bt[o] - m * sc);
}

// L1: in 64 (from maxh/minh + scale0/shift0 + lrelu), out 64. Wave-per-row.
__global__ __launch_bounds__(256) void l1_kernel(const float* __restrict__ maxh,
        const float* __restrict__ minh, const float* __restrict__ s0, const float* __restrict__ t0,
        const float* __restrict__ w1, const float* __restrict__ b1,
        float* __restrict__ y1, double* __restrict__ sum1, double* __restrict__ sq1)
{
    __shared__ float wl[64*64];          // 16 KB
    __shared__ double red[4][64][2];
    for (int i = threadIdx.x; i < 64*64; i += 256) wl[i] = w1[i];
    const int wv = threadIdx.x >> 6, lane = threadIdx.x & 63;
    const float sc = s0[lane], sh = t0[lane], bo = b1[lane];
    const bool usemax = (sc >= 0.f);
    double dsum = 0.0, dsq = 0.0;
    __syncthreads();
    const int rbase = (blockIdx.x * 4 + wv) * 32;
    for (int r = rbase; r < rbase + 32; ++r) {
        const size_t off = (size_t)r * 64 + lane;
        float xv = usemax ? maxh[off] : minh[off];
        float a = lrelu(fmaf(sc, xv, sh));
        float y = bo;
#pragma unroll
        for (int c = 0; c < 64; ++c)
            y = fmaf(__shfl(a, c), wl[c*64 + lane], y);
        y1[off] = y;
        dsum += (double)y; dsq += (double)y * (double)y;
    }
    red[wv][lane][0] = dsum; red[wv][lane][1] = dsq;
    __syncthreads();
    if (wv == 0) {
        double s = red[0][lane][0]+red[1][lane][0]+red[2][lane][0]+red[3][lane][0];
        double q = red[0][lane][1]+red[1][lane][1]+red[2][lane][1]+red[3][lane][1];
        atomicAdd(&sum1[lane], s);
        atomicAdd(&sq1[lane], q);
    }
}

// L2: in 64, out 128 (lane handles o and o+64)
__global__ __launch_bounds__(256) void l2_kernel(const float* __restrict__ y1,
        const float* __restrict__ s1, const float* __restrict__ t1,
        const float* __restrict__ w2, const float* __restrict__ b2,
        float* __restrict__ y2, double* __restrict__ sum2, double* __restrict__ sq2)
{
    __shared__ float wl[64*128];         // 32 KB
    __shared__ double red[4][128][2];
    for (int i = threadIdx.x; i < 64*128; i += 256) wl[i] = w2[i];
    const int wv = threadIdx.x >> 6, lane = threadIdx.x & 63;
    const float sc = s1[lane], sh = t1[lane];
    const float blo = b2[lane], bhi = b2[lane+64];
    double dsl=0, dql=0, dshh=0, dqh=0;
    __syncthreads();
    const int rbase = (blockIdx.x * 4 + wv) * 32;
    for (int r = rbase; r < rbase + 32; ++r) {
        float a = lrelu(fmaf(sc, y1[(size_t)r*64 + lane], sh));
        float ylo = blo, yhi = bhi;
#pragma unroll
        for (int c = 0; c < 64; ++c) {
            float ac = __shfl(a, c);
            ylo = fmaf(ac, wl[c*128 + lane],      ylo);
            yhi = fmaf(ac, wl[c*128 + lane + 64], yhi);
        }
        y2[(size_t)r*128 + lane]      = ylo;
        y2[(size_t)r*128 + lane + 64] = yhi;
        dsl += (double)ylo; dql += (double)ylo*(double)ylo;
        dshh += (double)yhi; dqh += (double)yhi*(double)yhi;
    }
    red[wv][lane][0] = dsl;       red[wv][lane][1] = dql;
    red[wv][lane+64][0] = dshh;   red[wv][lane+64][1] = dqh;
    __syncthreads();
    if (wv < 2) {
        int ch = wv * 64 + lane;
        double s = red[0][ch][0]+red[1][ch][0]+red[2][ch][0]+red[3][ch][0];
        double q = red[0][ch][1]+red[1][ch][1]+red[2][ch][1]+red[3][ch][1];
        atomicAdd(&sum2[ch], s);
        atomicAdd(&sq2[ch], q);
    }
}

// L3: in 128, out 128 — split output into halves across blocks (LDS 32KB per half)
__global__ __launch_bounds__(256) void l3_kernel(const float* __restrict__ y2,
        const float* __restrict__ s2, const float* __restrict__ t2,
        const float* __restrict__ w3, const float* __restrict__ b3,
        float* __restrict__ y3, double* __restrict__ sum3, double* __restrict__ sq3)
{
    __shared__ float wl[128*64];         // 32 KB: w3[:, h*64 : h*64+64]
    __shared__ double red[4][64][2];
    const int h = blockIdx.x & 1;
    const int rchunk = blockIdx.x >> 1;
    for (int i = threadIdx.x; i < 128*64; i += 256) {
        int c = i >> 6, o = i & 63;
        wl[i] = w3[c*128 + h*64 + o];
    }
    const int wv = threadIdx.x >> 6, lane = threadIdx.x & 63;
    const float sclo = s2[lane],    shlo = t2[lane];
    const float schi = s2[lane+64], shhi = t2[lane+64];
    const float bo = b3[h*64 + lane];
    double dsum = 0, dsq = 0;
    __syncthreads();
    const int rbase = (rchunk * 4 + wv) * 32;
    for (int r = rbase; r < rbase + 32; ++r) {
        float alo = lrelu(fmaf(sclo, y2[(size_t)r*128 + lane],      shlo));
        float ahi = lrelu(fmaf(schi, y2[(size_t)r*128 + lane + 64], shhi));
        float y = bo;
#pragma unroll
        for (int c = 0; c < 64; ++c) {
            y = fmaf(__shfl(alo, c), wl[c*64 + lane],        y);
            y = fmaf(__shfl(ahi, c), wl[(c+64)*64 + lane],   y);
        }
        y3[(size_t)r*128 + h*64 + lane] = y;
        dsum += (double)y; dsq += (double)y * (double)y;
    }
    red[wv][lane][0] = dsum; red[wv][lane][1] = dsq;
    __syncthreads();
    if (wv == 0) {
        double s = red[0][lane][0]+red[1][lane][0]+red[2][lane][0]+red[3][lane][0];
        double q = red[0][lane][1]+red[1][lane][1]+red[2][lane][1]+red[3][lane][1];
        atomicAdd(&sum3[h*64 + lane], s);
        atomicAdd(&sq3[h*64 + lane], q);
    }
}

// max over N with BN+lrelu applied inline
__global__ __launch_bounds__(256) void pool_kernel(const float* __restrict__ y3,
        const float* __restrict__ s3, const float* __restrict__ t3, float* __restrict__ pooled)
{
    __shared__ float red[2][128];
    const int b = blockIdx.x;
    const int wv = threadIdx.x >> 6, lane = threadIdx.x & 63;
    const int ch = (wv & 1) * 64 + lane;
    const float sc = s3[ch], sh = t3[ch];
    float m = -__builtin_inff();
    const int n0 = (wv >> 1) * 1024;
    for (int n = n0; n < n0 + 1024; ++n) {
        float v = lrelu(fmaf(sc, y3[((size_t)b*NPTS + n)*128 + ch], sh));
        m = fmaxf(m, v);
    }
    red[wv >> 1][ch] = m;
    __syncthreads();
    if (threadIdx.x < 128)
        pooled[b*128 + threadIdx.x] = fmaxf(red[0][threadIdx.x], red[1][threadIdx.x]);
}

// head: (B,128) -> lrelu(@w4+b4) (512) -> @w5+b5 (256)
__global__ __launch_bounds__(256) void head_kernel(const float* __restrict__ pooled,
        const float* __restrict__ w4, const float* __restrict__ b4,
        const float* __restrict__ w5, const float* __restrict__ b5, float* __restrict__ out)
{
    __shared__ float xr[128];
    __shared__ float hh[512];
    const int b = blockIdx.x, t = threadIdx.x;
    if (t < 128) xr[t] = pooled[b*128 + t];
    __syncthreads();
    float h0 = b4[t], h1 = b4[t + 256];
    for (int c = 0; c < 128; ++c) {
        float xc = xr[c];
        h0 = fmaf(xc, w4[c*512 + t],       h0);
        h1 = fmaf(xc, w4[c*512 + t + 256], h1);
    }
    hh[t]       = lrelu(h0);
    hh[t + 256] = lrelu(h1);
    __syncthreads();
    float acc = b5[t];
    for (int c = 0; c < 512; ++c)
        acc = fmaf(hh[c], w5[c*256 + t], acc);
    out[b*256 + t] = acc;
}

extern "C" void kernel_launch(void* const* d_in, const int* in_sizes, int n_in,
                              void* d_out, int out_size, void* d_ws, size_t ws_size,
                              hipStream_t stream)
{
    const float* x      = (const float*)d_in[0];
    const float* conv_w = (const float*)d_in[1];
    const float* conv_g = (const float*)d_in[2];
    const float* conv_b = (const float*)d_in[3];
    const float* w1  = (const float*)d_in[4];
    const float* b1  = (const float*)d_in[5];
    const float* g1  = (const float*)d_in[6];
    const float* bt1 = (const float*)d_in[7];
    const float* w2  = (const float*)d_in[8];
    const float* b2  = (const float*)d_in[9];
    const float* g2  = (const float*)d_in[10];
    const float* bt2 = (const float*)d_in[11];
    const float* w3  = (const float*)d_in[12];
    const float* b3  = (const float*)d_in[13];
    const float* g3  = (const float*)d_in[14];
    const float* bt3 = (const float*)d_in[15];
    const float* w4  = (const float*)d_in[16];
    const float* b4  = (const float*)d_in[17];
    const float* w5  = (const float*)d_in[18];
    const float* b5  = (const float*)d_in[19];

    char* p = (char*)d_ws;
    auto take = [&](size_t bytes) -> char* {
        char* r = p; p += (bytes + 255) & ~(size_t)255; return r;
    };
    // zeroed accumulator region (must come first)
    double* S    = (double*)take(27 * 8);
    double* sum1 = (double*)take(64 * 8);
    double* sq1  = (double*)take(64 * 8);
    double* sum2 = (double*)take(128 * 8);
    double* sq2  = (double*)take(128 * 8);
    double* sum3 = (double*)take(128 * 8);
    double* sq3  = (double*)take(128 * 8);
    size_t zero_bytes = (size_t)(p - (char*)d_ws);
    // non-zeroed scratch
    float* scale0 = (float*)take(64 * 4);
    float* shift0 = (float*)take(64 * 4);
    float* scale1 = (float*)take(64 * 4);
    float* shift1 = (float*)take(64 * 4);
    float* scale2 = (float*)take(128 * 4);
    float* shift2 = (float*)take(128 * 4);
    float* scale3 = (float*)take(128 * 4);
    float* shift3 = (float*)take(128 * 4);
    float* pooled = (float*)take(NB * 128 * 4);
    int*   idx    = (int*)take((size_t)NROWS * KNBR * 4);          // 2.6 MB
    float* mm     = (float*)take((size_t)NROWS * 128 * 4);         // 16 MB: maxh|minh, later y3
    float* maxh   = mm;
    float* minh   = mm + (size_t)NROWS * 64;
    float* y1     = (float*)take((size_t)NROWS * 64 * 4);          // 8 MB
    float* y2     = (float*)take((size_t)NROWS * 128 * 4);         // 16 MB
    float* y3     = mm;   // alias: maxh/minh dead after l1 (stream-serial)

    hipMemsetAsync(d_ws, 0, zero_bytes, stream);
    knn_kernel  <<<dim3(NB * 8),      dim3(256), 0, stream>>>(x, idx);
    feat_kernel <<<dim3(NROWS / 32),  dim3(256), 0, stream>>>(x, idx, conv_w, maxh, minh, S);
    stats0_kernel<<<dim3(1),          dim3(64),  0, stream>>>(S, conv_w, conv_g, conv_b, scale0, shift0);
    l1_kernel   <<<dim3(256),         dim3(256), 0, stream>>>(maxh, minh, scale0, shift0, w1, b1, y1, sum1, sq1);
    statsL_kernel<<<dim3(1),          dim3(64),  0, stream>>>(sum1, sq1, g1, bt1, scale1, shift1, 64);
    l2_kernel   <<<dim3(256),         dim3(256), 0, stream>>>(y1, scale1, shift1, w2, b2, y2, sum2, sq2);
    statsL_kernel<<<dim3(1),          dim3(128), 0, stream>>>(sum2, sq2, g2, bt2, scale2, shift2, 128);
    l3_kernel   <<<dim3(512),         dim3(256), 0, stream>>>(y2, scale2, shift2, w3, b3, y3, sum3, sq3);
    statsL_kernel<<<dim3(1),          dim3(128), 0, stream>>>(sum3, sq3, g3, bt3, scale3, shift3, 128);
    pool_kernel <<<dim3(NB),          dim3(256), 0, stream>>>(y3, scale3, shift3, pooled);
    head_kernel <<<dim3(NB),          dim3(256), 0, stream>>>(pooled, w4, b4, w5, b5, (float*)d_out);
}

// Round 2
// 544.196 us; speedup vs baseline: 1.8502x; 1.8502x over previous
//
#include <hip/hip_runtime.h>
#include <math.h>

#define NB   16
#define NPTS 2048
#define KNBR 20
#define NCH  8            // knn chunks per query
#define CHSZ (NPTS/NCH)   // 256
#define NROWS (NB*NPTS)          // 32768
#define CONV_M ((double)(NB)*(double)(NPTS)*(double)(KNBR))
#define ROW_M  ((double)NROWS)
#define BN_EPS 1e-5
#define LSLOPE 0.2f

__device__ __forceinline__ float lrelu(float v) { return v >= 0.f ? v : LSLOPE * v; }

// pair-insert of (d0,d1) into sorted-desc bestv[20]; 3 ops/position via max/med3/min
__device__ __forceinline__ void pair_insert(float (&bestv)[KNBR], float d0, float d1)
{
    float t0 = fmaxf(d0, d1), t1 = fminf(d0, d1);
    if (t0 > bestv[KNBR-1]) {
#pragma unroll
        for (int j = 0; j < KNBR; ++j) {
            float bj = bestv[j];
            float nb  = fmaxf(bj, t0);
            float nt0 = __builtin_amdgcn_fmed3f(bj, t0, t1);
            float nt1 = fminf(bj, t1);          // == min3(bj,t0,t1) since t1<=t0
            bestv[j] = nb;
            t0 = nt0; t1 = nt1;
        }
    }
}

__device__ __forceinline__ float dist_eval(float4 q, float4 pm)
{
    float inner = __fadd_rn(__fadd_rn(__fmul_rn(q.x,pm.x), __fmul_rn(q.y,pm.y)), __fmul_rn(q.z,pm.z));
    return __fsub_rn(__fsub_rn(__fmul_rn(2.0f, inner), q.w), pm.w);
}

// ---------------------------------------------------------------------------
// KNN pass A: per (query, chunk-of-256) thread, exact top-20 values of chunk.
// Output P[(c*20+i)*NROWS + bq] (coalesced), sorted descending per (bq,c).
// ---------------------------------------------------------------------------
__global__ __launch_bounds__(256) void knn_part(const float* __restrict__ x,
                                                float* __restrict__ P)
{
    __shared__ float4 cpt[CHSZ];   // chunk candidates
    __shared__ float4 qpt[256];    // this block's queries
    const int b  = blockIdx.x >> 6;
    const int qg = (blockIdx.x >> 3) & 7;
    const int c  = blockIdx.x & 7;
    const float* xb = x + (size_t)b * NPTS * 3;
    {
        int j = c * CHSZ + threadIdx.x;
        float px = xb[j*3+0], py = xb[j*3+1], pz = xb[j*3+2];
        float xx = __fadd_rn(__fadd_rn(__fmul_rn(px,px), __fmul_rn(py,py)), __fmul_rn(pz,pz));
        cpt[threadIdx.x] = make_float4(px, py, pz, xx);
        int n = qg * 256 + threadIdx.x;
        px = xb[n*3+0]; py = xb[n*3+1]; pz = xb[n*3+2];
        xx = __fadd_rn(__fadd_rn(__fmul_rn(px,px), __fmul_rn(py,py)), __fmul_rn(pz,pz));
        qpt[threadIdx.x] = make_float4(px, py, pz, xx);
    }
    __syncthreads();
    const float4 q = qpt[threadIdx.x];
    float bestv[KNBR];
#pragma unroll
    for (int j = 0; j < KNBR; ++j) bestv[j] = -__builtin_inff();
    for (int m = 0; m < CHSZ; m += 2) {
        float d0 = dist_eval(q, cpt[m]);
        float d1 = dist_eval(q, cpt[m+1]);
        pair_insert(bestv, d0, d1);
    }
    const size_t bq = (size_t)b * NPTS + qg * 256 + threadIdx.x;
#pragma unroll
    for (int i = 0; i < KNBR; ++i)
        P[(size_t)(c * KNBR + i) * NROWS + bq] = bestv[i];
}

// ---------------------------------------------------------------------------
// KNN pass B: merge 8 sorted top-20 lists per query -> exact 20th-largest value
// ---------------------------------------------------------------------------
__global__ __launch_bounds__(256) void knn_merge(const float* __restrict__ P,
                                                 float* __restrict__ thresh)
{
    const size_t bq = (size_t)blockIdx.x * 256 + threadIdx.x;
    float bestv[KNBR];
#pragma unroll
    for (int j = 0; j < KNBR; ++j) bestv[j] = -__builtin_inff();
    for (int c = 0; c < NCH; ++c)
#pragma unroll
        for (int i = 0; i < KNBR; i += 2) {
            float d0 = P[(size_t)(c * KNBR + i)     * NROWS + bq];
            float d1 = P[(size_t)(c * KNBR + i + 1) * NROWS + bq];
            pair_insert(bestv, d0, d1);   // d0>=d1 already, pre-sort is free-ish
        }
    thresh[bq] = bestv[KNBR-1];
}

// ---------------------------------------------------------------------------
// KNN pass C: index recovery. Block = 32 queries x 8 splits; hits recorded in
// LDS, per-query prefix over splits, first-20 in ascending m (tie-exact).
// ---------------------------------------------------------------------------
__global__ __launch_bounds__(256) void knn_idx(const float* __restrict__ x,
        const float* __restrict__ thresh, int* __restrict__ idxo)
{
    __shared__ float4 pts[NPTS];              // 32 KB
    __shared__ unsigned char hitb[32][NCH][KNBR];
    __shared__ int cnts[32][NCH];
    const int b  = blockIdx.x >> 6;
    const int qg = blockIdx.x & 63;
    const float* xb = x + (size_t)b * NPTS * 3;
    for (int i = threadIdx.x; i < NPTS; i += 256) {
        float px = xb[i*3+0], py = xb[i*3+1], pz = xb[i*3+2];
        float xx = __fadd_rn(__fadd_rn(__fmul_rn(px,px), __fmul_rn(py,py)), __fmul_rn(pz,pz));
        pts[i] = make_float4(px, py, pz, xx);
    }
    __syncthreads();
    const int qi = threadIdx.x >> 3;          // 0..31
    const int sp = threadIdx.x & 7;           // split 0..7
    const int n  = qg * 32 + qi;
    const float4 q = pts[n];
    const float th = thresh[(size_t)b * NPTS + n];
    int lc = 0;
    const int j0 = sp * CHSZ;
    for (int j = j0; j < j0 + CHSZ; ++j) {
        float d = dist_eval(q, pts[j]);
        if (d >= th) { if (lc < KNBR) hitb[qi][sp][lc] = (unsigned char)(j - j0); ++lc; }
    }
    cnts[qi][sp] = lc < KNBR ? lc : KNBR;
    __syncthreads();
    int base = 0;
    for (int s = 0; s < sp; ++s) base += cnts[qi][s];
    int* op = idxo + ((size_t)b * NPTS + n) * KNBR;
    const int lim = cnts[qi][sp];
    for (int l = 0; l < lim; ++l) {
        int r = base + l;
        if (r < KNBR) op[r] = j0 + (int)hitb[qi][sp][l];
    }
}

// ---------------------------------------------------------------------------
// Edge-conv: per point, feat[k][6]; h[k][o] = feat.cw_o ; track max/min over k.
// Also accumulate feat moments S1[6], S2[21] (double) for factored BN stats.
// ---------------------------------------------------------------------------
__global__ __launch_bounds__(256) void feat_kernel(const float* __restrict__ x,
        const int* __restrict__ idx, const float* __restrict__ conv_w,
        float* __restrict__ maxh, float* __restrict__ minh, double* __restrict__ S)
{
    __shared__ float  featw[4][KNBR][6];
    __shared__ double sred[4][27];
    const int wv = threadIdx.x >> 6, lane = threadIdx.x & 63;
    float cw[6];
#pragma unroll
    for (int c = 0; c < 6; ++c) cw[c] = conv_w[lane*6 + c];
    int pa_ = 0, pb_ = 0;
    if (lane >= 6 && lane < 27) {
        int t = lane - 6, a = 0;
        while (t >= 6 - a) { t -= 6 - a; ++a; }
        pa_ = a; pb_ = a + t;
    }
    double acc = 0.0;
    for (int i = 0; i < 8; ++i) {
        const int bp = blockIdx.x * 32 + wv * 8 + i;
        const int b = bp >> 11, n = bp & (NPTS - 1);
        const float* xb = x + (size_t)b * NPTS * 3;
        const float xi0 = xb[n*3+0], xi1 = xb[n*3+1], xi2 = xb[n*3+2];
        float f0=0,f1=0,f2=0,f3=0,f4=0,f5=0;
        if (lane < KNBR) {
            const int nj = idx[(size_t)bp * KNBR + lane];
            f0 = xb[nj*3+0] - xi0; f1 = xb[nj*3+1] - xi1; f2 = xb[nj*3+2] - xi2;
            f3 = xi0; f4 = xi1; f5 = xi2;
        }
        __syncthreads();
        if (lane < KNBR) {
            featw[wv][lane][0]=f0; featw[wv][lane][1]=f1; featw[wv][lane][2]=f2;
            featw[wv][lane][3]=f3; featw[wv][lane][4]=f4; featw[wv][lane][5]=f5;
        }
        __syncthreads();
        float vmax = -__builtin_inff(), vmin = __builtin_inff();
#pragma unroll
        for (int k = 0; k < KNBR; ++k) {
            float h = featw[wv][k][0] * cw[0];
            h = fmaf(featw[wv][k][1], cw[1], h);
            h = fmaf(featw[wv][k][2], cw[2], h);
            h = fmaf(featw[wv][k][3], cw[3], h);
            h = fmaf(featw[wv][k][4], cw[4], h);
            h = fmaf(featw[wv][k][5], cw[5], h);
            vmax = fmaxf(vmax, h); vmin = fminf(vmin, h);
        }
        maxh[(size_t)bp*64 + lane] = vmax;
        minh[(size_t)bp*64 + lane] = vmin;
        if (lane < 6) {
            double s = 0;
#pragma unroll
            for (int k = 0; k < KNBR; ++k) s += (double)featw[wv][k][lane];
            acc += s;
        } else if (lane < 27) {
            double s = 0;
#pragma unroll
            for (int k = 0; k < KNBR; ++k)
                s += (double)featw[wv][k][pa_] * (double)featw[wv][k][pb_];
            acc += s;
        }
    }
    if (lane < 27) sred[wv][lane] = acc;
    __syncthreads();
    if (threadIdx.x < 27) {
        double tot = sred[0][threadIdx.x] + sred[1][threadIdx.x]
                   + sred[2][threadIdx.x] + sred[3][threadIdx.x];
        atomicAdd(&S[threadIdx.x], tot);
    }
}

__global__ void stats0_kernel(const double* __restrict__ S, const float* __restrict__ conv_w,
        const float* __restrict__ g, const float* __restrict__ bb,
        float* __restrict__ scale, float* __restrict__ shift)
{
    const int o = threadIdx.x;
    double w[6];
#pragma unroll
    for (int c = 0; c < 6; ++c) w[c] = (double)conv_w[o*6 + c];
    double mean = 0.0;
#pragma unroll
    for (int c = 0; c < 6; ++c) mean += w[c] * S[c];
    mean /= CONV_M;
    double ey2 = 0.0;
    int t = 6;
#pragma unroll
    for (int a = 0; a < 6; ++a)
#pragma unroll
        for (int b2 = a; b2 < 6; ++b2) {
            double coef = (a == b2) ? 1.0 : 2.0;
            ey2 += coef * w[a] * w[b2] * S[t];
            ++t;
        }
    ey2 /= CONV_M;
    double var = ey2 - mean * mean;
    double sc = (double)g[o] / sqrt(var + BN_EPS);
    scale[o] = (float)sc;
    shift[o] = (float)((double)bb[o] - mean * sc);
}

__global__ void statsL_kernel(const double* __restrict__ sum, const double* __restrict__ sq,
        const float* __restrict__ g, const float* __restrict__ bt,
        float* __restrict__ scale, float* __restrict__ shift, int C)
{
    const int o = threadIdx.x;
    if (o >= C) return;
    double m = sum[o] / ROW_M;
    double v = sq[o] / ROW_M - m * m;
    double sc = (double)g[o] / sqrt(v + BN_EPS);
    scale[o] = (float)sc;
    shift[o] = (float)((double)bt[o] - m * sc);
}

__global__ __launch_bounds__(256) void l1_kernel(const float* __restrict__ maxh,
        const float* __restrict__ minh, const float* __restrict__ s0, const float* __restrict__ t0,
        const float* __restrict__ w1, const float* __restrict__ b1,
        float* __restrict__ y1, double* __restrict__ sum1, double* __restrict__ sq1)
{
    __shared__ float wl[64*64];
    __shared__ double red[4][64][2];
    for (int i = threadIdx.x; i < 64*64; i += 256) wl[i] = w1[i];
    const int wv = threadIdx.x >> 6, lane = threadIdx.x & 63;
    const float sc = s0[lane], sh = t0[lane], bo = b1[lane];
    const bool usemax = (sc >= 0.f);
    double dsum = 0.0, dsq = 0.0;
    __syncthreads();
    const int rbase = (blockIdx.x * 4 + wv) * 32;
    for (int r = rbase; r < rbase + 32; ++r) {
        const size_t off = (size_t)r * 64 + lane;
        float xv = usemax ? maxh[off] : minh[off];
        float a = lrelu(fmaf(sc, xv, sh));
        float y = bo;
#pragma unroll
        for (int c = 0; c < 64; ++c)
            y = fmaf(__shfl(a, c), wl[c*64 + lane], y);
        y1[off] = y;
        dsum += (double)y; dsq += (double)y * (double)y;
    }
    red[wv][lane][0] = dsum; red[wv][lane][1] = dsq;
    __syncthreads();
    if (wv == 0) {
        double s = red[0][lane][0]+red[1][lane][0]+red[2][lane][0]+red[3][lane][0];
        double q = red[0][lane][1]+red[1][lane][1]+red[2][lane][1]+red[3][lane][1];
        atomicAdd(&sum1[lane], s);
        atomicAdd(&sq1[lane], q);
    }
}

__global__ __launch_bounds__(256) void l2_kernel(const float* __restrict__ y1,
        const float* __restrict__ s1, const float* __restrict__ t1,
        const float* __restrict__ w2, const float* __restrict__ b2,
        float* __restrict__ y2, double* __restrict__ sum2, double* __restrict__ sq2)
{
    __shared__ float wl[64*128];
    __shared__ double red[4][128][2];
    for (int i = threadIdx.x; i < 64*128; i += 256) wl[i] = w2[i];
    const int wv = threadIdx.x >> 6, lane = threadIdx.x & 63;
    const float sc = s1[lane], sh = t1[lane];
    const float blo = b2[lane], bhi = b2[lane+64];
    double dsl=0, dql=0, dshh=0, dqh=0;
    __syncthreads();
    const int rbase = (blockIdx.x * 4 + wv) * 32;
    for (int r = rbase; r < rbase + 32; ++r) {
        float a = lrelu(fmaf(sc, y1[(size_t)r*64 + lane], sh));
        float ylo = blo, yhi = bhi;
#pragma unroll
        for (int c = 0; c < 64; ++c) {
            float ac = __shfl(a, c);
            ylo = fmaf(ac, wl[c*128 + lane],      ylo);
            yhi = fmaf(ac, wl[c*128 + lane + 64], yhi);
        }
        y2[(size_t)r*128 + lane]      = ylo;
        y2[(size_t)r*128 + lane + 64] = yhi;
        dsl += (double)ylo; dql += (double)ylo*(double)ylo;
        dshh += (double)yhi; dqh += (double)yhi*(double)yhi;
    }
    red[wv][lane][0] = dsl;       red[wv][lane][1] = dql;
    red[wv][lane+64][0] = dshh;   red[wv][lane+64][1] = dqh;
    __syncthreads();
    if (wv < 2) {
        int ch = wv * 64 + lane;
        double s = red[0][ch][0]+red[1][ch][0]+red[2][ch][0]+red[3][ch][0];
        double q = red[0][ch][1]+red[1][ch][1]+red[2][ch][1]+red[3][ch][1];
        atomicAdd(&sum2[ch], s);
        atomicAdd(&sq2[ch], q);
    }
}

__global__ __launch_bounds__(256) void l3_kernel(const float* __restrict__ y2,
        const float* __restrict__ s2, const float* __restrict__ t2,
        const float* __restrict__ w3, const float* __restrict__ b3,
        float* __restrict__ y3, double* __restrict__ sum3, double* __restrict__ sq3)
{
    __shared__ float wl[128*64];
    __shared__ double red[4][64][2];
    const int h = blockIdx.x & 1;
    const int rchunk = blockIdx.x >> 1;
    for (int i = threadIdx.x; i < 128*64; i += 256) {
        int c = i >> 6, o = i & 63;
        wl[i] = w3[c*128 + h*64 + o];
    }
    const int wv = threadIdx.x >> 6, lane = threadIdx.x & 63;
    const float sclo = s2[lane],    shlo = t2[lane];
    const float schi = s2[lane+64], shhi = t2[lane+64];
    const float bo = b3[h*64 + lane];
    double dsum = 0, dsq = 0;
    __syncthreads();
    const int rbase = (rchunk * 4 + wv) * 32;
    for (int r = rbase; r < rbase + 32; ++r) {
        float alo = lrelu(fmaf(sclo, y2[(size_t)r*128 + lane],      shlo));
        float ahi = lrelu(fmaf(schi, y2[(size_t)r*128 + lane + 64], shhi));
        float y = bo;
#pragma unroll
        for (int c = 0; c < 64; ++c) {
            y = fmaf(__shfl(alo, c), wl[c*64 + lane],        y);
            y = fmaf(__shfl(ahi, c), wl[(c+64)*64 + lane],   y);
        }
        y3[(size_t)r*128 + h*64 + lane] = y;
        dsum += (double)y; dsq += (double)y * (double)y;
    }
    red[wv][lane][0] = dsum; red[wv][lane][1] = dsq;
    __syncthreads();
    if (wv == 0) {
        double s = red[0][lane][0]+red[1][lane][0]+red[2][lane][0]+red[3][lane][0];
        double q = red[0][lane][1]+red[1][lane][1]+red[2][lane][1]+red[3][lane][1];
        atomicAdd(&sum3[h*64 + lane], s);
        atomicAdd(&sq3[h*64 + lane], q);
    }
}

// pool stage 1: max over 128-point slab with BN+lrelu inline; 256 blocks
__global__ __launch_bounds__(256) void pool1_kernel(const float* __restrict__ y3,
        const float* __restrict__ s3, const float* __restrict__ t3, float* __restrict__ pp)
{
    const int b = blockIdx.x >> 4, ns = blockIdx.x & 15;
    const int wv = threadIdx.x >> 6, lane = threadIdx.x & 63;
    const int ch = (wv & 1) * 64 + lane;
    const float sc = s3[ch], sh = t3[ch];
    float m = -__builtin_inff();
    const int n0 = ns * 128 + (wv >> 1) * 64;
    for (int n = n0; n < n0 + 64; ++n) {
        float v = lrelu(fmaf(sc, y3[((size_t)b*NPTS + n)*128 + ch], sh));
        m = fmaxf(m, v);
    }
    __shared__ float red[2][128];
    red[wv >> 1][ch] = m;
    __syncthreads();
    if (threadIdx.x < 128)
        pp[((size_t)b*16 + ns)*128 + threadIdx.x] = fmaxf(red[0][threadIdx.x], red[1][threadIdx.x]);
}

__global__ void pool2_kernel(const float* __restrict__ pp, float* __restrict__ pooled)
{
    const int b = blockIdx.x, ch = threadIdx.x;   // 128 threads
    float m = -__builtin_inff();
    for (int ns = 0; ns < 16; ++ns)
        m = fmaxf(m, pp[((size_t)b*16 + ns)*128 + ch]);
    pooled[b*128 + ch] = m;
}

__global__ __launch_bounds__(256) void head_kernel(const float* __restrict__ pooled,
        const float* __restrict__ w4, const float* __restrict__ b4,
        const float* __restrict__ w5, const float* __restrict__ b5, float* __restrict__ out)
{
    __shared__ float xr[128];
    __shared__ float hh[512];
    const int b = blockIdx.x, t = threadIdx.x;
    if (t < 128) xr[t] = pooled[b*128 + t];
    __syncthreads();
    float h0 = b4[t], h1 = b4[t + 256];
    for (int c = 0; c < 128; ++c) {
        float xc = xr[c];
        h0 = fmaf(xc, w4[c*512 + t],       h0);
        h1 = fmaf(xc, w4[c*512 + t + 256], h1);
    }
    hh[t]       = lrelu(h0);
    hh[t + 256] = lrelu(h1);
    __syncthreads();
    float acc = b5[t];
    for (int c = 0; c < 512; ++c)
        acc = fmaf(hh[c], w5[c*256 + t], acc);
    out[b*256 + t] = acc;
}

extern "C" void kernel_launch(void* const* d_in, const int* in_sizes, int n_in,
                              void* d_out, int out_size, void* d_ws, size_t ws_size,
                              hipStream_t stream)
{
    const float* x      = (const float*)d_in[0];
    const float* conv_w = (const float*)d_in[1];
    const float* conv_g = (const float*)d_in[2];
    const float* conv_b = (const float*)d_in[3];
    const float* w1  = (const float*)d_in[4];
    const float* b1  = (const float*)d_in[5];
    const float* g1  = (const float*)d_in[6];
    const float* bt1 = (const float*)d_in[7];
    const float* w2  = (const float*)d_in[8];
    const float* b2  = (const float*)d_in[9];
    const float* g2  = (const float*)d_in[10];
    const float* bt2 = (const float*)d_in[11];
    const float* w3  = (const float*)d_in[12];
    const float* b3  = (const float*)d_in[13];
    const float* g3  = (const float*)d_in[14];
    const float* bt3 = (const float*)d_in[15];
    const float* w4  = (const float*)d_in[16];
    const float* b4  = (const float*)d_in[17];
    const float* w5  = (const float*)d_in[18];
    const float* b5  = (const float*)d_in[19];

    char* p = (char*)d_ws;
    auto take = [&](size_t bytes) -> char* {
        char* r = p; p += (bytes + 255) & ~(size_t)255; return r;
    };
    double* S    = (double*)take(27 * 8);
    double* sum1 = (double*)take(64 * 8);
    double* sq1  = (double*)take(64 * 8);
    double* sum2 = (double*)take(128 * 8);
    double* sq2  = (double*)take(128 * 8);
    double* sum3 = (double*)take(128 * 8);
    double* sq3  = (double*)take(128 * 8);
    size_t zero_bytes = (size_t)(p - (char*)d_ws);
    float* scale0 = (float*)take(64 * 4);
    float* shift0 = (float*)take(64 * 4);
    float* scale1 = (float*)take(64 * 4);
    float* shift1 = (float*)take(64 * 4);
    float* scale2 = (float*)take(128 * 4);
    float* shift2 = (float*)take(128 * 4);
    float* scale3 = (float*)take(128 * 4);
    float* shift3 = (float*)take(128 * 4);
    float* pooled = (float*)take(NB * 128 * 4);
    float* pp     = (float*)take((size_t)NB * 16 * 128 * 4);       // pool partials
    float* thresh = (float*)take((size_t)NROWS * 4);               // knn thresholds
    int*   idx    = (int*)take((size_t)NROWS * KNBR * 4);          // 2.6 MB
    float* mm     = (float*)take((size_t)NROWS * 128 * 4);         // 16 MB
    float* maxh   = mm;
    float* minh   = mm + (size_t)NROWS * 64;
    float* y1     = (float*)take((size_t)NROWS * 64 * 4);          // 8 MB
    float* y2     = (float*)take((size_t)NROWS * 128 * 4);         // 16 MB
    float* y3     = mm;          // alias (maxh/minh dead after l1)
    float* P      = mm;          // alias: knn partials (21 MB over mm+y1), dead before feat

    hipMemsetAsync(d_ws, 0, zero_bytes, stream);
    knn_part  <<<dim3(NB * 8 * NCH), dim3(256), 0, stream>>>(x, P);
    knn_merge <<<dim3(NROWS / 256),  dim3(256), 0, stream>>>(P, thresh);
    knn_idx   <<<dim3(NB * 64),      dim3(256), 0, stream>>>(x, thresh, idx);
    feat_kernel <<<dim3(NROWS / 32), dim3(256), 0, stream>>>(x, idx, conv_w, maxh, minh, S);
    stats0_kernel<<<dim3(1),         dim3(64),  0, stream>>>(S, conv_w, conv_g, conv_b, scale0, shift0);
    l1_kernel   <<<dim3(256),        dim3(256), 0, stream>>>(maxh, minh, scale0, shift0, w1, b1, y1, sum1, sq1);
    statsL_kernel<<<dim3(1),         dim3(64),  0, stream>>>(sum1, sq1, g1, bt1, scale1, shift1, 64);
    l2_kernel   <<<dim3(256),        dim3(256), 0, stream>>>(y1, scale1, shift1, w2, b2, y2, sum2, sq2);
    statsL_kernel<<<dim3(1),         dim3(128), 0, stream>>>(sum2, sq2, g2, bt2, scale2, shift2, 128);
    l3_kernel   <<<dim3(512),        dim3(256), 0, stream>>>(y2, scale2, shift2, w3, b3, y3, sum3, sq3);
    statsL_kernel<<<dim3(1),         dim3(128), 0, stream>>>(sum3, sq3, g3, bt3, scale3, shift3, 128);
    pool1_kernel<<<dim3(NB * 16),    dim3(256), 0, stream>>>(y3, scale3, shift3, pp);
    pool2_kernel<<<dim3(NB),         dim3(128), 0, stream>>>(pp, pooled);
    head_kernel <<<dim3(NB),         dim3(256), 0, stream>>>(pooled, w4, b4, w5, b5, (float*)d_out);
}